// Round 10
// baseline (84.876 us; speedup 1.0000x reference)
//
#include <hip/hip_runtime.h>

#define NW 10
typedef float f32x2 __attribute__((ext_vector_type(2)));

// ---- VOP3P packed fp32 helpers (R7-proven) ----
__device__ __forceinline__ f32x2 pk_mul(f32x2 a, f32x2 b) {
    f32x2 d;
    asm("v_pk_mul_f32 %0, %1, %2" : "=v"(d) : "v"(a), "v"(b));
    return d;
}
__device__ __forceinline__ f32x2 pk_fma(f32x2 a, f32x2 b, f32x2 c) {
    f32x2 d;
    asm("v_pk_fma_f32 %0, %1, %2, %3" : "=v"(d) : "v"(a), "v"(b), "v"(c));
    return d;
}
// d = a * swap2(b) + c   (swap folded into op_sel on src1)
__device__ __forceinline__ f32x2 pk_fma_sw1(f32x2 a, f32x2 b, f32x2 c) {
    f32x2 d;
    asm("v_pk_fma_f32 %0, %1, %2, %3 op_sel:[0,1,0] op_sel_hi:[1,0,1]"
        : "=v"(d) : "v"(a), "v"(b), "v"(c));
    return d;
}
__device__ __forceinline__ f32x2 sp2(float x)   { return f32x2{ x,  x}; }
__device__ __forceinline__ f32x2 sp2pm(float x) { return f32x2{ x, -x}; }

// DPP partner fetch: 0xB1 = lane xor 1, 0x4E = lane xor 2 (intra-quad)
template<int CTRL>
__device__ __forceinline__ f32x2 dpp2(f32x2 v) {
    f32x2 d;
    d.x = __int_as_float(__builtin_amdgcn_mov_dpp(__float_as_int(v.x), CTRL, 0xF, 0xF, true));
    d.y = __int_as_float(__builtin_amdgcn_mov_dpp(__float_as_int(v.y), CTRL, 0xF, 0xF, true));
    return d;
}

// CNOT-ring fused permutation (GF(2)-linear): psi_final[i] = psi_in[gperm(i)].
__device__ __forceinline__ int gperm(int v) {
    #pragma unroll
    for (int k = 9; k >= 0; --k) {
        const int cs = 9 - k;
        const int ts = 9 - ((k + 1) % NW);
        v ^= ((v >> cs) & 1) << ts;
    }
    return v;
}

// Padded physical float index (R3-proven; 16B alignment preserved).
__device__ __forceinline__ int PF(int i) {
    return i + ((i >> 5) << 2) + ((i >> 8) << 3);
}
#define STATE_MAX 1172          // PF(1023) = 1171
#define NRM0      1172          // 2 norm partials (imb plane)
#define RED0      1176          // 20 reduction slots (reb plane)
#define PBUF      1196          // floats per plane

// B-layout constant part for amp index a (bits a0,a1,a2 -> i bits 9,8,7)
__device__ __forceinline__ int brevC(int a) {
    return ((a & 1) << 9) | ((a & 2) << 7) | ((a & 4) << 5);
}

__device__ __forceinline__ float rl(float v, int lane) {
    return __int_as_float(__builtin_amdgcn_readlane(__float_as_int(v), lane));
}

// ---- complex gate [[a,b],[-conj(b),conj(a)]] between vec pairs, dist D (4 vecs) ----
template<int D>
__device__ __forceinline__ void cgv(f32x2* rf, f32x2* mf,
                                    float ar, float ai, float br, float bi) {
    const f32x2 sAr = sp2(ar),  sAi  = sp2(ai),  sAiN = sp2(-ai);
    const f32x2 sBr = sp2(br),  sBrN = sp2(-br);
    const f32x2 sBi = sp2(bi),  sBiN = sp2(-bi);
    #pragma unroll
    for (int base = 0; base < 4; base += 2 * D) {
        #pragma unroll
        for (int off = 0; off < D; ++off) {
            const int j0 = base + off, j1 = j0 + D;
            const f32x2 v0r = rf[j0], v0i = mf[j0];
            const f32x2 v1r = rf[j1], v1i = mf[j1];
            f32x2 t = pk_mul(sAr, v0r);
            t = pk_fma(sAiN, v0i, t); t = pk_fma(sBr, v1r, t);
            rf[j0] = pk_fma(sBiN, v1i, t);
            t = pk_mul(sAr, v0i);
            t = pk_fma(sAi, v0r, t);  t = pk_fma(sBr, v1i, t);
            mf[j0] = pk_fma(sBi, v1r, t);
            t = pk_mul(sAr, v1r);
            t = pk_fma(sAi, v1i, t);  t = pk_fma(sBrN, v0r, t);
            rf[j1] = pk_fma(sBiN, v0i, t);
            t = pk_mul(sAr, v1i);
            t = pk_fma(sAiN, v1r, t); t = pk_fma(sBrN, v0i, t);
            mf[j1] = pk_fma(sBi, v0r, t);
        }
    }
}

// complex gate WITHIN each f32x2 (element 0 = bit-0 side) — R7-verified body
__device__ __forceinline__ void cgv0(f32x2* rf, f32x2* mf,
                                     float ar, float ai, float br, float bi) {
    const f32x2 sAr  = sp2(ar);
    const f32x2 sAiN = f32x2{-ai, ai};
    const f32x2 sAiP = sp2pm(ai);
    const f32x2 sBrN = sp2pm(br);
    const f32x2 sBiN = sp2(-bi);
    const f32x2 sBi  = sp2(bi);
    #pragma unroll
    for (int j = 0; j < 4; ++j) {
        const f32x2 vr = rf[j], vi = mf[j];
        f32x2 t = pk_mul(sAr, vr);
        t = pk_fma(sAiN, vi, t);
        t = pk_fma_sw1(sBrN, vr, t);
        rf[j] = pk_fma_sw1(sBiN, vi, t);
        t = pk_mul(sAr, vi);
        t = pk_fma(sAiP, vr, t);
        t = pk_fma_sw1(sBrN, vi, t);
        mf[j] = pk_fma_sw1(sBi, vr, t);
    }
}

// complex gate on a lane bit via DPP; sg = +1 on bit==0 side — R8-verified body
template<int CTRL>
__device__ __forceinline__ void cgd(f32x2* rf, f32x2* mf, float sg,
                                    float ar, float ai, float br, float bi) {
    const f32x2 sAr   = sp2(ar);
    const f32x2 sAiS  = sp2(sg * ai);
    const f32x2 sAiSN = sp2(-sg * ai);
    const f32x2 sBrS  = sp2(sg * br);
    const f32x2 sBi   = sp2(bi);
    const f32x2 sBiN  = sp2(-bi);
    #pragma unroll
    for (int j = 0; j < 4; ++j) {
        const f32x2 orr = rf[j], oii = mf[j];
        const f32x2 prr = dpp2<CTRL>(orr), pii = dpp2<CTRL>(oii);
        f32x2 t = pk_mul(sAr, orr);
        t = pk_fma(sAiSN, oii, t);
        t = pk_fma(sBrS, prr, t);
        rf[j] = pk_fma(sBiN, pii, t);
        t = pk_mul(sAr, oii);
        t = pk_fma(sAiS, orr, t);
        t = pk_fma(sBrS, pii, t);
        mf[j] = pk_fma(sBi, prr, t);
    }
}

// real RY between vec pairs, dist D (4 vecs)
template<int D>
__device__ __forceinline__ void rgv(f32x2* rf, f32x2* mf, float c, float s) {
    const f32x2 sC = sp2(c), sS = sp2(s), sSN = sp2(-s);
    #pragma unroll
    for (int base = 0; base < 4; base += 2 * D) {
        #pragma unroll
        for (int off = 0; off < D; ++off) {
            const int j0 = base + off, j1 = j0 + D;
            const f32x2 v0r = rf[j0], v0i = mf[j0];
            const f32x2 v1r = rf[j1], v1i = mf[j1];
            rf[j0] = pk_fma(sSN, v1r, pk_mul(sC, v0r));
            mf[j0] = pk_fma(sSN, v1i, pk_mul(sC, v0i));
            rf[j1] = pk_fma(sC, v1r, pk_mul(sS, v0r));
            mf[j1] = pk_fma(sC, v1i, pk_mul(sS, v0i));
        }
    }
}

// real RY WITHIN each f32x2 — R7-verified body
__device__ __forceinline__ void rgv0(f32x2* rf, f32x2* mf, float c, float s) {
    const f32x2 sC = sp2(c), sSN = f32x2{-s, s};
    #pragma unroll
    for (int j = 0; j < 4; ++j) {
        const f32x2 vr = rf[j], vi = mf[j];
        rf[j] = pk_fma_sw1(sSN, vr, pk_mul(sC, vr));
        mf[j] = pk_fma_sw1(sSN, vi, pk_mul(sC, vi));
    }
}

// real RY on a lane bit via DPP — R8-verified body
template<int CTRL>
__device__ __forceinline__ void rgd(f32x2* rf, f32x2* mf, float sg, float c, float s) {
    const f32x2 sC = sp2(c), sS = sp2(-sg * s);
    #pragma unroll
    for (int j = 0; j < 4; ++j) {
        rf[j] = pk_fma(sS, dpp2<CTRL>(rf[j]), pk_mul(sC, rf[j]));
        mf[j] = pk_fma(sS, dpp2<CTRL>(mf[j]), pk_mul(sC, mf[j]));
    }
}

// 128 threads (2 waves) per block = per state. 8 amps/thread as 4 f32x2.
// Layout A: i = u<<3 | a   (a bits -> wires 9,8,7; u0,u1 -> wires 6,5 DPP; u2..u6 -> wires 4..0)
// Layout B: i = bitrev10(A): a bits -> i bits 9,8,7 (wires 0,1,2); u0,u1 -> bits 6,5 (wires 3,4 DPP)
__global__ __launch_bounds__(128, 8) void qsa_main(
    const float* __restrict__ x,
    const float* __restrict__ rx0,
    const float* __restrict__ ry0,
    const float* __restrict__ ry1,
    float* __restrict__ out) {

    __shared__ __align__(16) float reb[PBUF];
    __shared__ __align__(16) float imb[PBUF];

    const int u    = threadIdx.x;
    const int lane = u & 63;
    const int wave = u >> 6;
    const int n    = blockIdx.x;

    // ---- load 8 floats (layout A: amps u*8 .. u*8+7) ----
    f32x2 rf[4], mf[4];
    const float* xr = x + ((size_t)n << 10) + (u << 3);
    {
        const float4 v0 = *reinterpret_cast<const float4*>(xr);
        const float4 v1 = *reinterpret_cast<const float4*>(xr + 4);
        rf[0] = f32x2{v0.x, v0.y}; rf[1] = f32x2{v0.z, v0.w};
        rf[2] = f32x2{v1.x, v1.y}; rf[3] = f32x2{v1.z, v1.w};
    }

    // ---- per-wire coefficients in lanes 0..9 of EACH wave ----
    float car = 0.f, cai = 0.f, cbr = 0.f, cbi = 0.f, cc1 = 0.f, cs1 = 0.f;
    if (lane < NW) {
        float sx, cx, sy0, cy0;
        sincosf(0.5f * rx0[lane], &sx,  &cx);
        sincosf(0.5f * ry0[lane], &sy0, &cy0);
        sincosf(0.5f * ry1[lane], &cs1, &cc1);
        car =  cy0 * cx;  cai =  sy0 * sx;   // fused RY(ry0)*RX(rx0)
        cbr = -sy0 * cx;  cbi = -cy0 * sx;
    }

    // ---- norm partial (deferred: scale^2 applied to final probabilities) ----
    {
        f32x2 ssv = {0.f, 0.f};
        #pragma unroll
        for (int j = 0; j < 4; ++j) ssv += rf[j] * rf[j];
        float ss = ssv.x + ssv.y;
        #pragma unroll
        for (int b = 32; b > 0; b >>= 1) ss += __shfl_xor(ss, b, 64);
        if (lane == 0) imb[NRM0 + wave] = ss;
    }

    const float sg1 = (u & 1) ? -1.f : 1.f;   // u bit 0
    const float sg2 = (u & 2) ? -1.f : 1.f;   // u bit 1

    // ========= layer 1 in A: wires 9,8,7 (regs) + 6,5 (DPP) =========
    {   // wire 9 (within-pair, real input, no scale)
        const float ar = rl(car,9), ai = rl(cai,9), br = rl(cbr,9), bi = rl(cbi,9);
        const f32x2 sAr  = sp2(ar);
        const f32x2 sAiP = sp2pm(ai);
        const f32x2 sBrN = sp2pm(br);
        const f32x2 sBi  = sp2(bi);
        #pragma unroll
        for (int j = 0; j < 4; ++j) {
            const f32x2 v = rf[j];
            rf[j] = pk_fma_sw1(sBrN, v, pk_mul(sAr, v));
            mf[j] = pk_fma_sw1(sBi,  v, pk_mul(sAiP, v));
        }
    }
    cgv<1>(rf, mf, rl(car,8), rl(cai,8), rl(cbr,8), rl(cbi,8));         // wire 8
    cgv<2>(rf, mf, rl(car,7), rl(cai,7), rl(cbr,7), rl(cbi,7));         // wire 7
    cgd<0xB1>(rf, mf, sg1, rl(car,6), rl(cai,6), rl(cbr,6), rl(cbi,6)); // wire 6
    cgd<0x4E>(rf, mf, sg2, rl(car,5), rl(cai,5), rl(cbr,5), rl(cbi,5)); // wire 5

    // T1: write A (contiguous b128), read B (b32 + const offsets)
    const int PA = (u << 3) + ((u >> 2) << 2) + ((u >> 5) << 3);   // PF(u<<3)
    *reinterpret_cast<float4*>(&reb[PA])     = make_float4(rf[0].x, rf[0].y, rf[1].x, rf[1].y);
    *reinterpret_cast<float4*>(&reb[PA + 4]) = make_float4(rf[2].x, rf[2].y, rf[3].x, rf[3].y);
    *reinterpret_cast<float4*>(&imb[PA])     = make_float4(mf[0].x, mf[0].y, mf[1].x, mf[1].y);
    *reinterpret_cast<float4*>(&imb[PA + 4]) = make_float4(mf[2].x, mf[2].y, mf[3].x, mf[3].y);
    __syncthreads();
    const int Lb = ((u & 1) << 6) | ((u & 2) << 4) | ((u & 4) << 2) | (u & 8)
                 | ((u & 16) >> 2) | ((u & 32) >> 4) | ((u & 64) >> 6);  // bitrev7(u)
    const int PL = Lb + ((Lb >> 5) << 2);   // PF(Lb), Lb < 128
    #pragma unroll
    for (int j = 0; j < 4; ++j) {
        const int o0 = PF(brevC(2*j)), o1 = PF(brevC(2*j + 1));   // const-fold
        rf[j] = f32x2{reb[PL + o0], reb[PL + o1]};
        mf[j] = f32x2{imb[PL + o0], imb[PL + o1]};
    }

    // ========= layer 1 in B: wires 0,1,2 (regs) + 3,4 (DPP) =========
    cgv0  (rf, mf, rl(car,0), rl(cai,0), rl(cbr,0), rl(cbi,0));         // wire 0
    cgv<1>(rf, mf, rl(car,1), rl(cai,1), rl(cbr,1), rl(cbi,1));         // wire 1
    cgv<2>(rf, mf, rl(car,2), rl(cai,2), rl(cbr,2), rl(cbi,2));         // wire 2
    cgd<0xB1>(rf, mf, sg1, rl(car,3), rl(cai,3), rl(cbr,3), rl(cbi,3)); // wire 3
    cgd<0x4E>(rf, mf, sg2, rl(car,4), rl(cai,4), rl(cbr,4), rl(cbi,4)); // wire 4

    // T2: write own B slots (no barrier needed: only this lane reads/writes them),
    //     then CNOT-ring gather (cross-lane) after barrier.
    #pragma unroll
    for (int j = 0; j < 4; ++j) {
        const int o0 = PF(brevC(2*j)), o1 = PF(brevC(2*j + 1));
        reb[PL + o0] = rf[j].x; reb[PL + o1] = rf[j].y;
        imb[PL + o0] = mf[j].x; imb[PL + o1] = mf[j].y;
    }
    __syncthreads();
    {
        const int gL = gperm(Lb);
        #pragma unroll
        for (int j = 0; j < 4; ++j) {
            const int x0 = gL ^ gperm(brevC(2*j));        // gperm(const) folds
            const int x1 = gL ^ gperm(brevC(2*j + 1));
            const int p0 = PF(x0), p1 = PF(x1);
            rf[j] = f32x2{reb[p0], reb[p1]};
            mf[j] = f32x2{imb[p0], imb[p1]};
        }
    }

    // ========= layer 2 in B: wires 0,1,2 (regs) + 3,4 (DPP) =========
    rgv0  (rf, mf, rl(cc1,0), rl(cs1,0));            // wire 0
    rgv<1>(rf, mf, rl(cc1,1), rl(cs1,1));            // wire 1
    rgv<2>(rf, mf, rl(cc1,2), rl(cs1,2));            // wire 2
    rgd<0xB1>(rf, mf, sg1, rl(cc1,3), rl(cs1,3));    // wire 3
    rgd<0x4E>(rf, mf, sg2, rl(cc1,4), rl(cs1,4));    // wire 4

    // T3: barrier (protect gather readers), write own B slots, barrier, read A
    __syncthreads();
    #pragma unroll
    for (int j = 0; j < 4; ++j) {
        const int o0 = PF(brevC(2*j)), o1 = PF(brevC(2*j + 1));
        reb[PL + o0] = rf[j].x; reb[PL + o1] = rf[j].y;
        imb[PL + o0] = mf[j].x; imb[PL + o1] = mf[j].y;
    }
    __syncthreads();
    {
        const float4 q0 = *reinterpret_cast<const float4*>(&reb[PA]);
        const float4 q1 = *reinterpret_cast<const float4*>(&reb[PA + 4]);
        const float4 q2 = *reinterpret_cast<const float4*>(&imb[PA]);
        const float4 q3 = *reinterpret_cast<const float4*>(&imb[PA + 4]);
        rf[0] = f32x2{q0.x, q0.y}; rf[1] = f32x2{q0.z, q0.w};
        rf[2] = f32x2{q1.x, q1.y}; rf[3] = f32x2{q1.z, q1.w};
        mf[0] = f32x2{q2.x, q2.y}; mf[1] = f32x2{q2.z, q2.w};
        mf[2] = f32x2{q3.x, q3.y}; mf[3] = f32x2{q3.z, q3.w};
    }

    // ========= layer 2 in A: wires 9,8,7 (regs) + 6,5 (DPP) =========
    rgv0  (rf, mf, rl(cc1,9), rl(cs1,9));            // wire 9
    rgv<1>(rf, mf, rl(cc1,8), rl(cs1,8));            // wire 8
    rgv<2>(rf, mf, rl(cc1,7), rl(cs1,7));            // wire 7
    rgd<0xB1>(rf, mf, sg1, rl(cc1,6), rl(cs1,6));    // wire 6
    rgd<0x4E>(rf, mf, sg2, rl(cc1,5), rl(cs1,5));    // wire 5

    // ---- Z expectations in A (i = u<<3 | a) ----
    const float sst    = imb[NRM0] + imb[NRM0 + 1];
    const float scale2 = 1.0f / fmaxf(sst, 1e-24f);   // == (1/max(||x||,eps))^2

    f32x2 accP = {0,0}, acc9 = {0,0}, acc8 = {0,0}, acc7 = {0,0};
    const f32x2 pm = {1.f, -1.f};
    #pragma unroll
    for (int j = 0; j < 4; ++j) {
        const f32x2 p = rf[j]*rf[j] + mf[j]*mf[j];
        accP += p;
        acc9 += pm * p;                       // wire 9 <- a bit0
        if (j & 1) acc8 -= p; else acc8 += p; // wire 8 <- a bit1
        if (j & 2) acc7 -= p; else acc7 += p; // wire 7 <- a bit2
    }
    float P  = (accP.x + accP.y) * scale2;
    float a9 = (acc9.x + acc9.y) * scale2;
    float a8 = (acc8.x + acc8.y) * scale2;
    float a7 = (acc7.x + acc7.y) * scale2;
    #pragma unroll
    for (int b = 1; b < 64; b <<= 1) {
        a9 += __shfl_xor(a9, b, 64);
        a8 += __shfl_xor(a8, b, 64);
        a7 += __shfl_xor(a7, b, 64);
        const float e = __shfl_xor(P, b, 64);
        P = (lane & b) ? (e - P) : (e + P);   // WHT over intra-wave lane bits
    }
    // red layout per wave: [0]=a9 [1]=a8 [2]=a7 [3]=W(0) [4..9]=W(1,2,4,8,16,32)
    const int rb = RED0 + wave * 10;
    if (lane == 0) { reb[rb] = a9; reb[rb+1] = a8; reb[rb+2] = a7; reb[rb+3] = P; }
    if (lane == 1)  reb[rb+4] = P;   // wire 6 <- u bit0
    if (lane == 2)  reb[rb+5] = P;   // wire 5 <- u bit1
    if (lane == 4)  reb[rb+6] = P;   // wire 4 <- u bit2
    if (lane == 8)  reb[rb+7] = P;   // wire 3 <- u bit3
    if (lane == 16) reb[rb+8] = P;   // wire 2 <- u bit4
    if (lane == 32) reb[rb+9] = P;   // wire 1 <- u bit5
    __syncthreads();
    if (u < NW) {
        // wire u: u==0 -> W(0) with wave sign (u6 = wave bit); else sum both waves
        const int i0 = (u == 0) ? 3 : (u <= 6 ? 10 - u : 9 - u);
        const float lo = reb[RED0 + i0], hi = reb[RED0 + 10 + i0];
        out[(size_t)n * NW + u] = (u == 0) ? (lo - hi) : (lo + hi);
    }
}

extern "C" void kernel_launch(void* const* d_in, const int* in_sizes, int n_in,
                              void* d_out, int out_size, void* d_ws, size_t ws_size,
                              hipStream_t stream) {
    const float* x   = (const float*)d_in[0];
    const float* rx0 = (const float*)d_in[1];
    const float* ry0 = (const float*)d_in[2];
    const float* ry1 = (const float*)d_in[3];
    float* out = (float*)d_out;
    const int nstates = in_sizes[0] >> 10;   // 4096
    qsa_main<<<nstates, 128, 0, stream>>>(x, rx0, ry0, ry1, out);
}